// Round 19
// baseline (146.770 us; speedup 1.0000x reference)
//
#include <hip/hip_runtime.h>
#include <stdint.h>

// ============================================================================
// Fused attention block: out = proj( MHA_causal( x @ w_attn + b_attn ) )
// B=4, S=2048, E=1024, H=16, D=64.  bf16 MFMA path, f32 accumulation.
//
// Pipeline:
//   1) cast_x_kernel:        x f32 -> xb bf16                  [8192][1024]
//   2) transpose_cast:       w_attn -> wat bf16 [3072][1024] (B^T form)
//                            w_proj -> wpt bf16 [1024][1024]
//   3) gemm256<bf16,FUSE_VT>: qkv(Q,K) + vt(V) = xb @ wat^T + b [8192][3072]
//        BK=32, triple-buffer, counted vmcnt(3), 1 barrier/K-tile.
//        V-blocks: coalesced vt epilogue; key-permute = swap bits 2<->3
//        (matches flash v12's 32x32 in-lane P pack; involution).
//        Q columns (<1024) pre-scaled by log2e/8 for exp2-domain softmax.
//   4) flash_kernel v12:     ob = causal attention             [8192][1024]
//        32x32x16 MFMA; 8 waves = 4 q-groups x 2 KEY-HALVES. Each wave:
//        S^T(32k x 32q) = 4 MFMA / 4 ds_read_b128; partial O over its keys
//        = 4 MFMA / 4 reads -> HALF the LDS reads per q-row of v6 (which was
//        LDS-pipe-bound at 80%). No-max softmax => key-split partials are
//        additive; one f32 LDS merge per q-tile. Paired (bx,15-bx), 512
//        blocks, 2/CU, 16 waves/CU, XCD-affinity remap.
//   5) gemm128<float>:       out = ob @ wpt^T + b_proj         [8192][1024]
// ============================================================================

typedef __bf16 bf16;
typedef __bf16 bf16x4 __attribute__((ext_vector_type(4)));
typedef __bf16 bf16x8 __attribute__((ext_vector_type(8)));
typedef float  f32x4  __attribute__((ext_vector_type(4)));
typedef float  f32x16 __attribute__((ext_vector_type(16)));

#define DEV __device__ __forceinline__

// async global->LDS, 16B per lane. LDS dest: wave-uniform base; HW adds lane*16.
DEV void async_copy16(bf16* lds, const bf16* g) {
  __builtin_amdgcn_global_load_lds(
      (__attribute__((address_space(1))) void*)(uintptr_t)g,
      (__attribute__((address_space(3))) void*)(uint32_t)(uintptr_t)lds,
      16, 0, 0);
}

// ---------------------------------------------------------------------------
// prep kernels
// ---------------------------------------------------------------------------
__global__ __launch_bounds__(256) void cast_x_kernel(const float* __restrict__ in,
                                                     bf16* __restrict__ out, int n4) {
  int i = blockIdx.x * blockDim.x + threadIdx.x;
  int stride = gridDim.x * blockDim.x;
  for (; i < n4; i += stride) {
    float4 v = ((const float4*)in)[i];
    bf16x4 o = { (bf16)v.x, (bf16)v.y, (bf16)v.z, (bf16)v.w };
    *(bf16x4*)(out + (size_t)i * 4) = o;
  }
}

// W [Kd][Nd] f32 row-major  ->  Wt [Nd][Kd] bf16 row-major
__global__ __launch_bounds__(256) void transpose_cast_kernel(const float* __restrict__ W,
                                                             bf16* __restrict__ Wt,
                                                             int Kd, int Nd) {
  __shared__ alignas(16) bf16 T[64 * 80];   // 64x64 tile, padded rows
  const int t = threadIdx.x;
  const int n0 = blockIdx.x * 64;
  const int k0 = blockIdx.y * 64;
#pragma unroll
  for (int i = 0; i < 4; ++i) {
    int idx = t + i * 256;            // 1024 float4s
    int r  = idx >> 4;                // k row in tile
    int c4 = (idx & 15) * 4;          // n col in tile
    float4 v = *(const float4*)(W + (size_t)(k0 + r) * Nd + n0 + c4);
    bf16x4 o = { (bf16)v.x, (bf16)v.y, (bf16)v.z, (bf16)v.w };
    *(bf16x4*)(&T[r * 80 + c4]) = o;
  }
  __syncthreads();
#pragma unroll
  for (int i = 0; i < 2; ++i) {
    int idx = t + i * 256;            // 512 out-chunks
    int n = idx >> 3;
    int c = idx & 7;
    bf16x8 o;
#pragma unroll
    for (int j = 0; j < 8; ++j) o[j] = T[(c * 8 + j) * 80 + n];
    *(bf16x8*)(Wt + (size_t)(n0 + n) * Kd + k0 + c * 8) = o;
  }
}

// ---------------------------------------------------------------------------
// GEMM gemm256: C[M][N] = A[M][K] @ Bt[N][K]^T + bias[N]
// BM=256, BN=128, BK=32. 512 thr = 8 waves (4M x 2N), 64x64 per wave.
// Triple-buffered LDS (72 KB, 2 blocks/CU), one barrier/K-tile, counted
// vmcnt(3), slot^=(row>>1)&3 swizzle, XCD-bijective block swizzle.
// FUSE_VT + n0>=2048: coalesced vt epilogue; key permute = swap bits 2,3.
// ---------------------------------------------------------------------------
template <typename OutT, bool FUSE_VT>
__global__ __launch_bounds__(512, 4) void gemm256_kernel(const bf16* __restrict__ A,
                                                         const bf16* __restrict__ Bt,
                                                         const float* __restrict__ bias,
                                                         OutT* __restrict__ C,
                                                         bf16* __restrict__ vtout,
                                                         int M, int N, int K,
                                                         float qscale, int qcols,
                                                         int nbx) {
  __shared__ alignas(16) char smem[73728];               // 72 KB
  auto As = (bf16(*)[256 * 32])smem;                     // As[3][8192] (48 KB)
  auto Bs = (bf16(*)[128 * 32])(smem + 49152);           // Bs[3][4096] (24 KB)

  const int tid  = threadIdx.x;
  const int lane = tid & 63;
  const int w    = tid >> 6;
  const int wm = w >> 1, wn = w & 1;
  const int l15 = lane & 15, l16 = lane >> 4;

  const int nwg = (int)gridDim.x;
  const int cpx = nwg >> 3;
  const int swz = ((int)blockIdx.x & 7) * cpx + ((int)blockIdx.x >> 3);
  const int m0 = (swz / nbx) * 256;
  const int n0 = (swz % nbx) * 128;

  const int c0  = w * 64 + lane;                 // chunk for A j=0 and B
  const int rA0 = c0 >> 2, sA0 = c0 & 3;
  const int rA1 = rA0 + 128;                     // A j=1 (c0+512)
  const bf16* srcA0 = A  + (size_t)(m0 + rA0) * K + 8 * (sA0 ^ ((rA0 >> 1) & 3));
  const bf16* srcA1 = A  + (size_t)(m0 + rA1) * K + 8 * (sA0 ^ ((rA1 >> 1) & 3));
  const bf16* srcB  = Bt + (size_t)(n0 + rA0) * K + 8 * (sA0 ^ ((rA0 >> 1) & 3));

#define STAGE_TILE(buf, kt)                                       \
  {                                                               \
    const int k0_ = (kt) * 32;                                    \
    async_copy16(&As[buf][(w * 64) * 8],         srcA0 + k0_);    \
    async_copy16(&As[buf][(512 + w * 64) * 8],   srcA1 + k0_);    \
    async_copy16(&Bs[buf][(w * 64) * 8],         srcB  + k0_);    \
  }

  f32x4 acc[4][4];
  f32x4 zf = {0.f, 0.f, 0.f, 0.f};
#pragma unroll
  for (int i = 0; i < 4; ++i)
#pragma unroll
    for (int j = 0; j < 4; ++j) acc[i][j] = zf;

  const int KT = K >> 5;
  STAGE_TILE(0, 0)
  STAGE_TILE(1, 1)

  const int soff = 8 * (l16 ^ ((l15 >> 1) & 3));

  int bufc = 0;
  int bufs = 2;
  for (int kt = 0; kt < KT; ++kt) {
    if (kt < KT - 1) { asm volatile("s_waitcnt vmcnt(3)" ::: "memory"); }
    else             { asm volatile("s_waitcnt vmcnt(0)" ::: "memory"); }
    __builtin_amdgcn_s_barrier();
    asm volatile("" ::: "memory");
    if (kt + 2 < KT) STAGE_TILE(bufs, kt + 2)

    bf16x8 bfr[4], afr[4];
#pragma unroll
    for (int n = 0; n < 4; ++n) {
      int rb = wn * 64 + n * 16 + l15;
      bfr[n] = *(const bf16x8*)(&Bs[bufc][rb * 32 + soff]);
    }
#pragma unroll
    for (int m = 0; m < 4; ++m) {
      int ra = wm * 64 + m * 16 + l15;
      afr[m] = *(const bf16x8*)(&As[bufc][ra * 32 + soff]);
    }
    __builtin_amdgcn_s_setprio(1);
#pragma unroll
    for (int m = 0; m < 4; ++m)
#pragma unroll
      for (int n = 0; n < 4; ++n)
        acc[m][n] = __builtin_amdgcn_mfma_f32_16x16x32_bf16(afr[m], bfr[n], acc[m][n], 0, 0, 0);
    __builtin_amdgcn_s_setprio(0);
    asm volatile("" ::: "memory");
    bufc = (bufc == 2) ? 0 : bufc + 1;
    bufs = (bufs == 2) ? 0 : bufs + 1;
  }

  // ---- epilogue
  if (FUSE_VT && n0 >= 2048) {
    // V-block: coalesced vt writes via LDS overlay T[128 cols][264 rows-pad].
    // Key permute = swap bits 2<->3 (pos(key0+j) = pos(key0)|j for aligned
    // quads since bits 0,1 are preserved; key0 % 4 == 0).
    __syncthreads();                         // all K-loop LDS reads complete
    bf16* T = (bf16*)smem;
#pragma unroll
    for (int n = 0; n < 4; ++n) {
      int c = wn * 64 + n * 16 + l15;
      float bb = bias[n0 + c];
#pragma unroll
      for (int m = 0; m < 4; ++m) {
        int r0_ = wm * 64 + m * 16 + l16 * 4;   // quad base row; key0 % 4 == 0
        int key0 = r0_ & 63;
        int pos0 = (key0 & 0x30) | ((key0 & 8) >> 1) | ((key0 & 4) << 1);
        int rp = (r0_ & ~63) | pos0;
        bf16x4 q = { (bf16)(acc[m][n][0] + bb), (bf16)(acc[m][n][1] + bb),
                     (bf16)(acc[m][n][2] + bb), (bf16)(acc[m][n][3] + bb) };
        *(bf16x4*)(&T[c * 264 + rp]) = q;
      }
    }
    __syncthreads();
    const int b_  = m0 >> 11;                // batch (tiles never straddle)
    const int s0_ = m0 & 2047;
    const int ck  = tid & 31;                // 16B chunk within a 512B run
#pragma unroll
    for (int pass = 0; pass < 8; ++pass) {
      int c = pass * 16 + (tid >> 5);        // 0..127
      int colg = n0 + c - 2048;
      int hh = colg >> 6, d = colg & 63;
      bf16x8 v = *(const bf16x8*)(&T[c * 264 + ck * 8]);
      *(bf16x8*)(vtout + ((size_t)(b_ * 16 + hh) * 64 + d) * 2048 + s0_ + ck * 8) = v;
    }
    return;
  }
  // Q/K columns: direct C writes
#pragma unroll
  for (int n = 0; n < 4; ++n) {
    int col = n0 + wn * 64 + n * 16 + l15;
    float bb = bias[col];
    float sc2 = (col < qcols) ? qscale : 1.0f;
#pragma unroll
    for (int m = 0; m < 4; ++m) {
#pragma unroll
      for (int reg = 0; reg < 4; ++reg) {
        int row = m0 + wm * 64 + m * 16 + l16 * 4 + reg;
        C[(size_t)row * N + col] = (OutT)((acc[m][n][reg] + bb) * sc2);
      }
    }
  }
#undef STAGE_TILE
}

// ---------------------------------------------------------------------------
// GEMM gemm128 (proj): BM=BN=128, BK=32, 256 thr = 4 waves (2x2), 64x64/wave.
// ---------------------------------------------------------------------------
template <typename OutT>
__global__ __launch_bounds__(256, 4) void gemm128_kernel(const bf16* __restrict__ A,
                                                         const bf16* __restrict__ Bt,
                                                         const float* __restrict__ bias,
                                                         OutT* __restrict__ C,
                                                         int M, int N, int K,
                                                         int nbx) {
  __shared__ alignas(16) char smem[49152];               // 48 KB
  auto As = (bf16(*)[128 * 32])smem;
  auto Bs = (bf16(*)[128 * 32])(smem + 24576);

  const int tid  = threadIdx.x;
  const int lane = tid & 63;
  const int w    = tid >> 6;          // 0..3
  const int wm = w >> 1, wn = w & 1;
  const int l15 = lane & 15, l16 = lane >> 4;

  const int nwg = (int)gridDim.x;
  const int cpx = nwg >> 3;
  const int swz = ((int)blockIdx.x & 7) * cpx + ((int)blockIdx.x >> 3);
  const int m0 = (swz / nbx) * 128;
  const int n0 = (swz % nbx) * 128;

  const int r0_ = tid >> 2, s0c = tid & 3;
  const int r1_ = r0_ + 64;
  const bf16* srcA0 = A  + (size_t)(m0 + r0_) * K + 8 * (s0c ^ ((r0_ >> 1) & 3));
  const bf16* srcA1 = A  + (size_t)(m0 + r1_) * K + 8 * (s0c ^ ((r1_ >> 1) & 3));
  const bf16* srcB0 = Bt + (size_t)(n0 + r0_) * K + 8 * (s0c ^ ((r0_ >> 1) & 3));
  const bf16* srcB1 = Bt + (size_t)(n0 + r1_) * K + 8 * (s0c ^ ((r1_ >> 1) & 3));

#define STAGE_TILE(buf, kt)                                         \
  {                                                                 \
    const int k0_ = (kt) * 32;                                      \
    async_copy16(&As[buf][(w * 64) * 8],         srcA0 + k0_);      \
    async_copy16(&As[buf][(256 + w * 64) * 8],   srcA1 + k0_);      \
    async_copy16(&Bs[buf][(w * 64) * 8],         srcB0 + k0_);      \
    async_copy16(&Bs[buf][(256 + w * 64) * 8],   srcB1 + k0_);      \
  }

  f32x4 acc[4][4];
  f32x4 zf = {0.f, 0.f, 0.f, 0.f};
#pragma unroll
  for (int i = 0; i < 4; ++i)
#pragma unroll
    for (int j = 0; j < 4; ++j) acc[i][j] = zf;

  const int KT = K >> 5;
  STAGE_TILE(0, 0)
  STAGE_TILE(1, 1)

  const int soff = 8 * (l16 ^ ((l15 >> 1) & 3));

  int bufc = 0;
  int bufs = 2;
  for (int kt = 0; kt < KT; ++kt) {
    if (kt < KT - 1) { asm volatile("s_waitcnt vmcnt(4)" ::: "memory"); }
    else             { asm volatile("s_waitcnt vmcnt(0)" ::: "memory"); }
    __builtin_amdgcn_s_barrier();
    asm volatile("" ::: "memory");
    if (kt + 2 < KT) STAGE_TILE(bufs, kt + 2)

    bf16x8 bfr[4], afr[4];
#pragma unroll
    for (int n = 0; n < 4; ++n) {
      int rb = wn * 64 + n * 16 + l15;
      bfr[n] = *(const bf16x8*)(&Bs[bufc][rb * 32 + soff]);
    }
#pragma unroll
    for (int m = 0; m < 4; ++m) {
      int ra = wm * 64 + m * 16 + l15;
      afr[m] = *(const bf16x8*)(&As[bufc][ra * 32 + soff]);
    }
    __builtin_amdgcn_s_setprio(1);
#pragma unroll
    for (int m = 0; m < 4; ++m)
#pragma unroll
      for (int n = 0; n < 4; ++n)
        acc[m][n] = __builtin_amdgcn_mfma_f32_16x16x32_bf16(afr[m], bfr[n], acc[m][n], 0, 0, 0);
    __builtin_amdgcn_s_setprio(0);
    asm volatile("" ::: "memory");
    bufc = (bufc == 2) ? 0 : bufc + 1;
    bufs = (bufs == 2) ? 0 : bufs + 1;
  }

#pragma unroll
  for (int n = 0; n < 4; ++n) {
    int col = n0 + wn * 64 + n * 16 + l15;
    float bb = bias[col];
#pragma unroll
    for (int m = 0; m < 4; ++m) {
#pragma unroll
      for (int reg = 0; reg < 4; ++reg) {
        int row = m0 + wm * 64 + m * 16 + l16 * 4 + reg;
        C[(size_t)row * N + col] = (OutT)(acc[m][n][reg] + bb);
      }
    }
  }
#undef STAGE_TILE
}

// ---------------------------------------------------------------------------
// Flash attention v12 (causal). 32x32x16 MFMA. Q-tile 128 rows.
// 8 waves = 4 q-groups (32 rows each) x 2 key-halves (32 keys of each
// 64-key step-tile). Per wave-step: S^T(32kx32q) = 4 MFMA + 4 ds_read_b128
// (K-frags); partial O^T(64dx32q over its keys) = 4 MFMA + 4 reads (V-frags)
// -- HALF of v6's LDS reads per q-row (v6 was LDS-pipe-bound).
// No-max exp2 softmax => key-half partials (O,l) are additive; merged once
// per q-tile via f32 LDS buffer. Paired (bx,15-bx) -> 36 steps/block;
// grid 512, XCD-affinity remap; LDS 64.5 KB -> 2 blocks/CU (16 waves/CU).
// Layouts (32x32x16): A/B row|col = lane&31, k = (lane>>5)*8+j.
// C/D: col = lane&31, row = (r&3) + 8*(r>>2) + 4*(lane>>5), r in [0,16).
// vt key axis pre-permuted by swap23 so PV's B-operand is the in-lane pack
// pb[kk] = bf16(sv[kk*8 .. kk*8+7]).
// ---------------------------------------------------------------------------
__global__ __launch_bounds__(512, 4) void flash_kernel(const bf16* __restrict__ qkv,
                                                       const bf16* __restrict__ vt,
                                                       bf16* __restrict__ obuf) {
  constexpr int S = 2048, E3 = 3072;
  __shared__ alignas(16) bf16 Ks[2][64 * 64];    // 16 KB
  __shared__ alignas(16) bf16 Vs[2][64 * 64];    // 16 KB (key-permuted cols)
  __shared__ alignas(16) float Ms[4][32][64];    // 32 KB merge buffer
  __shared__ float Ls[4][32];                    // 512 B

  const int tid  = threadIdx.x;
  const int lane = tid & 63;
  const int w    = tid >> 6;
  const int qg = w >> 1, kh = w & 1;          // q-group 0..3, key-half 0..1
  const int i   = (int)blockIdx.x;            // 0..511
  const int bh  = ((i >> 6) << 3) | (i & 7);  // same-bh blocks share i%8 (XCD)
  const int bx  = (i >> 3) & 7;               // 0..7 -> tiles bx and 15-bx
  const int b = bh >> 4, h = bh & 15;
  const int l31 = lane & 31, l5 = lane >> 5;

  // staging geometry (wave w stages 1KB chunk w of each 64x64 tile)
  const int sr  = w * 8 + (lane >> 3);
  const int scc = lane & 7;
  const bf16* kstage = qkv + (size_t)(b * S + sr) * E3 + 1024 + h * 64 + 8 * (scc ^ (sr & 7));
  const bf16* vstage = vt + (size_t)(bh * 64 + sr) * S + 8 * (scc ^ (sr & 7));

  // hoisted LDS byte offsets (slot swizzle: slot g of row r lives at g^(r&7))
  const int rK = kh * 32 + l31;               // key row for QK A-frags
  uint32_t offK[4];
#pragma unroll
  for (int dm = 0; dm < 4; ++dm)
    offK[dm] = (uint32_t)(rK * 128 + 16 * (((dm << 1) | l5) ^ (rK & 7)));
  uint32_t offV[2][2];
#pragma unroll
  for (int bd = 0; bd < 2; ++bd)
#pragma unroll
    for (int kk = 0; kk < 2; ++kk) {
      int rV = bd * 32 + l31;                 // d row for PV A-frags
      offV[bd][kk] = (uint32_t)(rV * 128 + 16 * (((kh << 2) | (kk << 1) | l5) ^ (rV & 7)));
    }

#define KV_STAGE(buf, kv0_)                                        \
  {                                                                \
    async_copy16(Ks[buf] + w * 512, kstage + (size_t)(kv0_) * E3); \
    async_copy16(Vs[buf] + w * 512, vstage + (kv0_));              \
  }

  const f32x16 z16 = {0.f,0.f,0.f,0.f,0.f,0.f,0.f,0.f,
                      0.f,0.f,0.f,0.f,0.f,0.f,0.f,0.f};

  for (int half = 0; half < 2; ++half) {
    const int t = half ? (15 - bx) : bx;
    const int q0 = t * 128;
    const int wq0 = q0 + qg * 32;        // first q row owned by this wave
    const int qrow = wq0 + l31;          // this lane's q row
    const int nsteps = 2 * t + 2;        // even

    KV_STAGE(0, 0)

    // Q fragments (B-operand: col q = l31, k = l5*8+j, per 16-d chunk mf)
    bf16x8 qf[4];
    {
      const bf16* qbase = qkv + (size_t)(b * S + qrow) * E3 + h * 64 + l5 * 8;
#pragma unroll
      for (int mf = 0; mf < 4; ++mf)
        qf[mf] = *(const bf16x8*)(qbase + mf * 16);
    }

    float lstate = 0.f;
    f32x16 oacc[2];
    oacc[0] = z16; oacc[1] = z16;

    __syncthreads();   // step-0 K/V staged (vmcnt drained by barrier)

#define FLASH_STEP(CUR, STEPIDX)                                                  \
    {                                                                             \
      const int kv0 = (STEPIDX) * 64;                                             \
      if ((STEPIDX) + 1 < nsteps) KV_STAGE((CUR) ^ 1, kv0 + 64)                   \
      if (kv0 + kh * 32 <= wq0 + 31) {   /* wave-uniform dead-step skip */        \
        f32x16 sv = z16;                                                          \
        __builtin_amdgcn_s_setprio(1);                                            \
        _Pragma("unroll")                                                         \
        for (int dm = 0; dm < 4; ++dm) {                                          \
          bf16x8 kfr = *(const bf16x8*)((const char*)Ks[CUR] + offK[dm]);         \
          sv = __builtin_amdgcn_mfma_f32_32x32x16_bf16(kfr, qf[dm], sv, 0, 0, 0); \
        }                                                                         \
        __builtin_amdgcn_s_setprio(0);                                            \
        if (kv0 + kh * 32 + 31 > wq0) {   /* causal mask (diagonal band) */       \
          _Pragma("unroll")                                                       \
          for (int r = 0; r < 16; ++r) {                                          \
            int key = kv0 + kh * 32 + (r & 3) + 8 * (r >> 2) + 4 * l5;            \
            if (key > qrow) sv[r] = -1e30f;                                       \
          }                                                                       \
        }                                                                         \
        float rsum = 0.f;                                                         \
        _Pragma("unroll")                                                         \
        for (int r = 0; r < 16; ++r) {                                            \
          float p = __builtin_amdgcn_exp2f(sv[r]);                                \
          sv[r] = p;                                                              \
          rsum += p;                                                              \
        }                                                                         \
        rsum += __shfl_xor(rsum, 32);                                             \
        lstate += rsum;                                                           \
        bf16x8 pb[2];                                                             \
        _Pragma("unroll")                                                         \
        for (int kk = 0; kk < 2; ++kk) {                                          \
          bf16x8 tq;                                                              \
          _Pragma("unroll")                                                       \
          for (int j = 0; j < 8; ++j) tq[j] = (bf16)sv[kk * 8 + j];               \
          pb[kk] = tq;                                                            \
        }                                                                         \
        __builtin_amdgcn_s_setprio(1);                                            \
        _Pragma("unroll")                                                         \
        for (int bd = 0; bd < 2; ++bd)                                            \
          _Pragma("unroll")                                                       \
          for (int kk = 0; kk < 2; ++kk) {                                        \
            bf16x8 vf = *(const bf16x8*)((const char*)Vs[CUR] + offV[bd][kk]);    \
            oacc[bd] = __builtin_amdgcn_mfma_f32_32x32x16_bf16(vf, pb[kk], oacc[bd], 0, 0, 0); \
          }                                                                       \
        __builtin_amdgcn_s_setprio(0);                                            \
      }                                                                           \
      __syncthreads();   /* next buffer staged + all waves done with CUR */       \
    }

    for (int step = 0; step < nsteps; step += 2) {
      FLASH_STEP(0, step)
      FLASH_STEP(1, step + 1)
    }
#undef FLASH_STEP

    // ---- merge key-half partials (additive: no-max softmax) and store.
    // oacc[bd][r] holds d = bd*32 + (r&3) + 8*(r>>2) + 4*l5 for q = l31.
    if (kh == 1) {
#pragma unroll
      for (int bd = 0; bd < 2; ++bd)
#pragma unroll
        for (int r4 = 0; r4 < 4; ++r4) {
          float4 q4 = { oacc[bd][r4 * 4 + 0], oacc[bd][r4 * 4 + 1],
                        oacc[bd][r4 * 4 + 2], oacc[bd][r4 * 4 + 3] };
          *(float4*)(&Ms[qg][l31][bd * 32 + 8 * r4 + 4 * l5]) = q4;
        }
      if (l5 == 0) Ls[qg][l31] = lstate;
    }
    __syncthreads();
    if (kh == 0) {
      float inv = 1.0f / (lstate + Ls[qg][l31]);
#pragma unroll
      for (int bd = 0; bd < 2; ++bd)
#pragma unroll
        for (int r4 = 0; r4 < 4; ++r4) {
          float4 p4 = *(const float4*)(&Ms[qg][l31][bd * 32 + 8 * r4 + 4 * l5]);
          bf16x4 o4 = { (bf16)((oacc[bd][r4 * 4 + 0] + p4.x) * inv),
                        (bf16)((oacc[bd][r4 * 4 + 1] + p4.y) * inv),
                        (bf16)((oacc[bd][r4 * 4 + 2] + p4.z) * inv),
                        (bf16)((oacc[bd][r4 * 4 + 3] + p4.w) * inv) };
          *(bf16x4*)(obuf + (size_t)(b * S + qrow) * 1024 + h * 64 + bd * 32 + 8 * r4 + 4 * l5) = o4;
        }
    }
    // next half: KV_STAGE targets Ks/Vs (not Ms); the post-stage barrier
    // orders kh=0's merge reads before any later Ms rewrite.
  }
#undef KV_STAGE
}

// ---------------------------------------------------------------------------
extern "C" void kernel_launch(void* const* d_in, const int* in_sizes, int n_in,
                              void* d_out, int out_size, void* d_ws, size_t ws_size,
                              hipStream_t stream) {
  (void)in_sizes; (void)n_in; (void)out_size; (void)ws_size;
  const float* x      = (const float*)d_in[0];
  const float* w_attn = (const float*)d_in[1];
  const float* b_attn = (const float*)d_in[2];
  const float* w_proj = (const float*)d_in[3];
  const float* b_proj = (const float*)d_in[4];
  float* out = (float*)d_out;

  char* ws = (char*)d_ws;
  bf16* xb  = (bf16*)(ws + 0);          // 8192*1024*2  = 16777216
  bf16* wat = (bf16*)(ws + 16777216);   // 3072*1024*2  =  6291456
  bf16* wpt = (bf16*)(ws + 23068672);   // 1024*1024*2  =  2097152
  bf16* qkv = (bf16*)(ws + 25165824);   // 8192*3072*2  = 50331648
  bf16* vt  = (bf16*)(ws + 75497472);   // 64*64*2048*2 = 16777216
  bf16* ob  = (bf16*)(ws + 92274688);   // 8192*1024*2  = 16777216 (end 109051904)

  const float QSCALE = 0.18033688011112042f;   // log2(e) / sqrt(64)

  cast_x_kernel<<<2048, 256, 0, stream>>>(x, xb, 8192 * 1024 / 4);
  transpose_cast_kernel<<<dim3(48, 16), 256, 0, stream>>>(w_attn, wat, 1024, 3072);
  transpose_cast_kernel<<<dim3(16, 16), 256, 0, stream>>>(w_proj, wpt, 1024, 1024);
  // QKV (+fused V-transpose): grid (8192/256)*(3072/128) = 768 blocks (%8==0)
  gemm256_kernel<bf16, true><<<768, 512, 0, stream>>>(xb, wat, b_attn, qkv, vt,
                                                      8192, 3072, 1024, QSCALE, 1024, 24);
  flash_kernel<<<512, 512, 0, stream>>>(qkv, vt, ob);
  // proj: grid (8192/128)*(1024/128) = 512 blocks (%8==0)
  gemm128_kernel<float><<<512, 256, 0, stream>>>(ob, wpt, b_proj, out,
                                                 8192, 1024, 1024, 8);
}